// Round 6
// baseline (169.560 us; speedup 1.0000x reference)
//
#include <hip/hip_runtime.h>
#include <hip/hip_bf16.h>
#include <cmath>

#define Bsz 8
#define Csz 512
#define Lsz 4096
#define LPOOL 511
#define NEGV -1000000000.0f

typedef __attribute__((ext_vector_type(8))) short short8;
typedef __attribute__((ext_vector_type(4))) float float4v;

__device__ __forceinline__ float bf2f(short u) {
  unsigned int x = ((unsigned int)(unsigned short)u) << 16;
  return __builtin_bit_cast(float, x);
}

// async global->LDS, 16B per lane. Global address is PER-LANE (must include
// lane term); LDS dest = wave-uniform base + lane*16 (HW-defined).
__device__ __forceinline__ void gl_lds16(const __hip_bfloat16* g, void* l) {
  __builtin_amdgcn_global_load_lds(
      (const __attribute__((address_space(1))) unsigned int*)g,
      (__attribute__((address_space(3))) unsigned int*)l, 16, 0, 0);
}

// ---------------------------------------------------------------------------
// stage1: flat grid 4096+129 blocks.
//  bid<4096: transpose tile -> xTs (tiled bf16 for MFMA) AND xbf (natural bf16)
//  bid>=4096: prep jobs: mask-width detect / convert W -> Wts tiled.
__global__ __launch_bounds__(256) void stage1(const float* __restrict__ x,
    __hip_bfloat16* __restrict__ xTs, __hip_bfloat16* __restrict__ xbf,
    const unsigned char* __restrict__ mb, int* __restrict__ flag,
    const float* __restrict__ W, __hip_bfloat16* __restrict__ Wts) {
  const int tid = threadIdx.x;
  const int bid = blockIdx.x;
  if (bid < 4096) {
    __shared__ float sX[64][65];               // 65 pitch: conflict-free
    const int lt = bid & 63, ct = (bid >> 6) & 7, b = bid >> 9;
    const int l0 = lt * 64;
    const float* xb = x + ((size_t)b * Csz + ct * 64) * Lsz + l0;
    #pragma unroll
    for (int it = 0; it < 4; ++it) {
      int c = it * 16 + (tid >> 4);
      int l = (tid & 15) * 4;
      *(float4*)(&sX[c][l]) = *(const float4*)(xb + (size_t)c * Lsz + l);
    }
    __syncthreads();
    // tiled layout for MFMA staging
    #pragma unroll
    for (int it = 0; it < 2; ++it) {
      int u = it * 256 + tid;
      int cg = u >> 6, ll = u & 63;
      __hip_bfloat16 hb[8];
      #pragma unroll
      for (int j = 0; j < 8; ++j)
        hb[j] = __float2bfloat16(sX[cg * 8 + j][ll]);
      int m = b * Lsz + l0 + ll;
      int mt = m >> 7, row = m & 127;
      int cglob = ct * 64 + cg * 8;
      int ks = cglob >> 5, seg = (cglob >> 3) & 3;
      *(short8*)(xTs + (((size_t)mt * 16 + ks) * 512 + seg * 128 + row) * 8) = *(short8*)hb;
    }
    // natural layout bf16 copy for pool
    #pragma unroll
    for (int it = 0; it < 2; ++it) {
      int u = it * 256 + tid;
      int cg = u >> 3, lseg = u & 7;
      __hip_bfloat16 hb[8];
      #pragma unroll
      for (int j = 0; j < 8; ++j)
        hb[j] = __float2bfloat16(sX[cg][lseg * 8 + j]);
      *(short8*)(xbf + ((size_t)b * Csz + ct * 64 + cg) * Lsz + l0 + lseg * 8) = *(short8*)hb;
    }
  } else {
    const int pb = bid - 4096;
    if (pb == 0) {
      __shared__ int sf;
      if (tid == 0) sf = 0;
      __syncthreads();
      int f = 0;
      for (int i = tid; i < 4096; i += 256)
        if ((i & 3) && mb[i]) f = 1;
      if (f) atomicOr(&sf, 1);
      __syncthreads();
      if (tid == 0) *flag = sf;  // 0 = int32 mask, 1 = uint8 mask
    } else {
      int tg = (pb - 1) * 256 + tid;
      int d = tg >> 6, cg = tg & 63;
      float4 w0 = *(const float4*)(W + (size_t)d * 512 + cg * 8);
      float4 w1 = *(const float4*)(W + (size_t)d * 512 + cg * 8 + 4);
      __hip_bfloat16 hb[8];
      hb[0] = __float2bfloat16(w0.x); hb[1] = __float2bfloat16(w0.y);
      hb[2] = __float2bfloat16(w0.z); hb[3] = __float2bfloat16(w0.w);
      hb[4] = __float2bfloat16(w1.x); hb[5] = __float2bfloat16(w1.y);
      hb[6] = __float2bfloat16(w1.z); hb[7] = __float2bfloat16(w1.w);
      int nt = d >> 7, row = d & 127, ks = cg >> 2, seg = cg & 3;
      *(short8*)(Wts + (((size_t)nt * 16 + ks) * 512 + seg * 128 + row) * 8) = *(short8*)hb;
    }
  }
}

// ---------------------------------------------------------------------------
// GEMM: s[m] = sum_{d=0..511} tanh((xT.WtT)[m,d]+bias[d])*v[d]
// One block per mt (128 m). 512 threads = 8 waves: wave = (nq<<1)|mh,
// wave tile 64m x 128n; full n=512 in one K pass -> no atomics, s written once.
__global__ __launch_bounds__(512, 2) void gemm_bf16(
    const __hip_bfloat16* __restrict__ xTs, const __hip_bfloat16* __restrict__ Wts,
    const float* __restrict__ bias, const float* __restrict__ v,
    float* __restrict__ s) {
  __shared__ short8 sAv[512];                  // [seg(4)][row(128)] 16B units, 8 KB
  __shared__ short8 sBv[2048];                 // [seg(4)][n(512)] 16B units, 32 KB
  __shared__ float s_acc[128];
  const int tid = threadIdx.x;
  const int lane = tid & 63, wave = tid >> 6;
  const int lr = lane & 15, quad = lane >> 4;
  const int mh = wave & 1, nq = wave >> 1;     // m-half (64), n-quarter (128)
  const int mt = blockIdx.x;
  const __hip_bfloat16* aT = xTs + (size_t)mt * 65536;   // 16 ks * 512 units * 8

  if (tid < 128) s_acc[tid] = 0.f;

  float bl[8], vl[8];
  #pragma unroll
  for (int nf = 0; nf < 8; ++nf) {
    int n = nq * 128 + nf * 16 + lr;
    bl[nf] = bias[n]; vl[nf] = v[n];
  }

  float4v acc[4][8];
  #pragma unroll
  for (int i = 0; i < 4; ++i)
    #pragma unroll
    for (int j = 0; j < 8; ++j) acc[i][j] = (float4v)0.f;

  for (int ks = 0; ks < 16; ++ks) {
    __syncthreads();
    // A: 512 units contiguous in xTs tile; 8 waves x 1 op (per-lane gaddr!)
    gl_lds16(aT + (size_t)ks * 4096 + (size_t)(wave * 64 + lane) * 8,
             &sAv[wave * 64]);
    // B: for each nt(4) x seg(4) x half(2): 64 contiguous units; 4 jobs/wave.
    #pragma unroll
    for (int it = 0; it < 4; ++it) {
      int job = wave * 4 + it;                 // 0..31
      int nt = job >> 3, seg = (job >> 1) & 3, half = job & 1;
      const __hip_bfloat16* gb = Wts +
          (((size_t)nt * 16 + ks) * 512 + seg * 128 + half * 64 + lane) * 8;
      gl_lds16(gb, &sBv[seg * 512 + nt * 128 + half * 64]);
    }
    __syncthreads();
    short8 af[4], bfr[8];
    #pragma unroll
    for (int mf = 0; mf < 4; ++mf)
      af[mf] = sAv[quad * 128 + mh * 64 + mf * 16 + lr];
    #pragma unroll
    for (int nf = 0; nf < 8; ++nf)
      bfr[nf] = sBv[quad * 512 + nq * 128 + nf * 16 + lr];
    #pragma unroll
    for (int mf = 0; mf < 4; ++mf)
      #pragma unroll
      for (int nf = 0; nf < 8; ++nf)
        acc[mf][nf] = __builtin_amdgcn_mfma_f32_16x16x32_bf16(af[mf], bfr[nf], acc[mf][nf], 0, 0, 0);
  }

  // Epilogue: C/D 16x16: n = lane&15, m = quad*4+reg. Reduce n: nf, then lanes.
  __syncthreads();
  #pragma unroll
  for (int mf = 0; mf < 4; ++mf) {
    #pragma unroll
    for (int reg = 0; reg < 4; ++reg) {
      float p = 0.f;
      #pragma unroll
      for (int nf = 0; nf < 8; ++nf)
        p += tanhf(acc[mf][nf][reg] + bl[nf]) * vl[nf];
      p += __shfl_xor(p, 1, 16);
      p += __shfl_xor(p, 2, 16);
      p += __shfl_xor(p, 4, 16);
      p += __shfl_xor(p, 8, 16);
      if (lr == 0)
        atomicAdd(&s_acc[mh * 64 + mf * 16 + quad * 4 + reg], p);
    }
  }
  __syncthreads();
  if (tid < 128) s[mt * 128 + tid] = s_acc[tid];
}

// ---------------------------------------------------------------------------
// pool2: fused windowed-softmax + pooling. Block = (8 p's) x (all 512 c) for
// one b. Softmax by 8 threads into LDS; then 32c x 8p threads, 16 c-iters,
// reading natural-layout bf16 x (two 16B loads per window, dense coalescing).
__global__ __launch_bounds__(256) void pool2(const __hip_bfloat16* __restrict__ xbf,
    const float* __restrict__ s, const void* __restrict__ mask,
    const int* __restrict__ flag, float* __restrict__ out) {
  __shared__ float wl[8][17];                  // 17 pitch: conflict-free
  const int t = threadIdx.x;
  const int p0 = blockIdx.x * 8, b = blockIdx.y;
  if (t < 8 && p0 + t < LPOOL) {
    const int p = p0 + t;
    const bool u8 = (*flag != 0);
    const unsigned char* m8 = (const unsigned char*)mask;
    const int* m32 = (const int*)mask;
    const int base = b * Lsz + p * 8;
    float sv[16]; int mv[16];
    float mx = -3.4e38f;
    #pragma unroll
    for (int w = 0; w < 16; ++w) {
      int mk = u8 ? (int)m8[base + w] : m32[base + w];
      float val = mk ? NEGV : s[base + w];
      sv[w] = val; mv[w] = mk;
      mx = fmaxf(mx, val);
    }
    float sum = 0.f;
    #pragma unroll
    for (int w = 0; w < 16; ++w) { sv[w] = expf(sv[w] - mx); sum += sv[w]; }
    float inv = 1.0f / sum;
    float norm = 0.f;
    #pragma unroll
    for (int w = 0; w < 16; ++w) { sv[w] = mv[w] ? 0.f : sv[w] * inv; norm += sv[w]; }
    norm = fmaxf(norm, 1e-6f);
    float rn = 1.0f / norm;
    #pragma unroll
    for (int w = 0; w < 16; ++w) wl[t][w] = sv[w] * rn;
  }
  __syncthreads();
  const int ci = t >> 3, pi = t & 7;
  const int p = p0 + pi;
  if (p >= LPOOL) return;
  float wr[16];
  #pragma unroll
  for (int w = 0; w < 16; ++w) wr[w] = wl[pi][w];
  #pragma unroll 4
  for (int it = 0; it < 16; ++it) {
    int c = it * 32 + ci;
    const __hip_bfloat16* xp = xbf + ((size_t)b * Csz + c) * Lsz + 8 * p;
    short8 lo = *(const short8*)xp;
    short8 hi = *(const short8*)(xp + 8);
    float acc = 0.f;
    #pragma unroll
    for (int j = 0; j < 8; ++j)
      acc += bf2f(lo[j]) * wr[j] + bf2f(hi[j]) * wr[8 + j];
    out[((size_t)b * Csz + c) * LPOOL + p] = acc;
  }
}

// ---------------------------------------------------------------------------
// Fallback path kernels (only if ws too small for bf16 path)
__global__ void detect_mask(const unsigned char* __restrict__ mb, int* __restrict__ flag) {
  __shared__ int sf;
  int t = threadIdx.x;
  if (t == 0) sf = 0;
  __syncthreads();
  int f = 0;
  for (int i = t; i < 4096; i += 256)
    if ((i & 3) && mb[i]) f = 1;
  if (f) atomicOr(&sf, 1);
  __syncthreads();
  if (t == 0) *flag = sf;
}

__global__ __launch_bounds__(256) void gemm_s_f32(const float* __restrict__ x,
    const float* __restrict__ W, const float* __restrict__ bias,
    const float* __restrict__ v, float* __restrict__ s_out) {
  __shared__ float sA[32][64];
  __shared__ float sB[32][68];
  __shared__ float s_acc[64];
  const int tid = threadIdx.x;
  const int b = blockIdx.y;
  const int l0 = blockIdx.x * 64;
  if (tid < 64) s_acc[tid] = 0.0f;
  const int tx = tid & 15;
  const int ty = tid >> 4;
  const float* xb = x + ((size_t)b * Csz) * Lsz + l0;
  for (int d0 = 0; d0 < Csz; d0 += 64) {
    float acc[4][4] = {{0.f}};
    for (int c0 = 0; c0 < Csz; c0 += 32) {
      __syncthreads();
      #pragma unroll
      for (int it = 0; it < 8; ++it) {
        int idx = tid + it * 256;
        int kc = idx >> 6, ml = idx & 63;
        sA[kc][ml] = xb[(size_t)(c0 + kc) * Lsz + ml];
      }
      #pragma unroll
      for (int it = 0; it < 8; ++it) {
        int idx = tid + it * 256;
        int kc = idx & 31, dj = idx >> 5;
        sB[kc][dj] = W[(size_t)(d0 + dj) * Csz + c0 + kc];
      }
      __syncthreads();
      #pragma unroll
      for (int kc = 0; kc < 32; ++kc) {
        float4 a  = *(const float4*)(&sA[kc][tx << 2]);
        float4 w4 = *(const float4*)(&sB[kc][ty << 2]);
        acc[0][0] += a.x * w4.x; acc[0][1] += a.x * w4.y; acc[0][2] += a.x * w4.z; acc[0][3] += a.x * w4.w;
        acc[1][0] += a.y * w4.x; acc[1][1] += a.y * w4.y; acc[1][2] += a.y * w4.z; acc[1][3] += a.y * w4.w;
        acc[2][0] += a.z * w4.x; acc[2][1] += a.z * w4.y; acc[2][2] += a.z * w4.z; acc[2][3] += a.z * w4.w;
        acc[3][0] += a.w * w4.x; acc[3][1] += a.w * w4.y; acc[3][2] += a.w * w4.z; acc[3][3] += a.w * w4.w;
      }
    }
    float part[4] = {0.f, 0.f, 0.f, 0.f};
    #pragma unroll
    for (int j = 0; j < 4; ++j) {
      int d = d0 + (ty << 2) + j;
      float bj = bias[d], vj = v[d];
      #pragma unroll
      for (int i = 0; i < 4; ++i)
        part[i] += tanhf(acc[i][j] + bj) * vj;
    }
    #pragma unroll
    for (int i = 0; i < 4; ++i)
      atomicAdd(&s_acc[(tx << 2) + i], part[i]);
  }
  __syncthreads();
  if (tid < 64) s_out[(size_t)b * Lsz + l0 + tid] = s_acc[tid];
}

__global__ void win_weights(const float* __restrict__ s, const void* __restrict__ mask,
                            const int* __restrict__ flag, float* __restrict__ wgt) {
  int t = blockIdx.x * blockDim.x + threadIdx.x;
  if (t >= Bsz * LPOOL) return;
  int b = t / LPOOL, p = t - b * LPOOL;
  const bool u8 = (*flag != 0);
  const unsigned char* m8 = (const unsigned char*)mask;
  const int* m32 = (const int*)mask;
  float sv[16]; int mv[16];
  float mx = -3.4e38f;
  int base = b * Lsz + p * 8;
  #pragma unroll
  for (int w = 0; w < 16; ++w) {
    int mk = u8 ? (int)m8[base + w] : m32[base + w];
    float val = mk ? NEGV : s[base + w];
    sv[w] = val; mv[w] = mk;
    mx = fmaxf(mx, val);
  }
  float sum = 0.f;
  #pragma unroll
  for (int w = 0; w < 16; ++w) { sv[w] = expf(sv[w] - mx); sum += sv[w]; }
  float inv = 1.0f / sum;
  float norm = 0.f;
  #pragma unroll
  for (int w = 0; w < 16; ++w) { sv[w] = mv[w] ? 0.f : sv[w] * inv; norm += sv[w]; }
  norm = fmaxf(norm, 1e-6f);
  float rn = 1.0f / norm;
  #pragma unroll
  for (int w = 0; w < 16; ++w) wgt[t * 16 + w] = sv[w] * rn;
}

__global__ __launch_bounds__(256) void pool_out(const float* __restrict__ x,
    const float* __restrict__ wgt, float* __restrict__ out) {
  __shared__ float xrow[Lsz];
  int bc = blockIdx.x;
  int c = bc & (Csz - 1);
  int b = bc >> 9;
  const float* xr = x + ((size_t)b * Csz + c) * Lsz;
  int tid = threadIdx.x;
  #pragma unroll
  for (int it = 0; it < 4; ++it) {
    int idx = (tid + it * 256) << 2;
    *(float4*)(&xrow[idx]) = *(const float4*)(&xr[idx]);
  }
  __syncthreads();
  const float* wb = wgt + (size_t)b * LPOOL * 16;
  float* ob = out + ((size_t)b * Csz + c) * LPOOL;
  for (int p = tid; p < LPOOL; p += 256) {
    const float4* wp = (const float4*)(wb + p * 16);
    const float4* xp = (const float4*)(&xrow[p * 8]);
    float acc = 0.f;
    #pragma unroll
    for (int q = 0; q < 4; ++q) {
      float4 wv = wp[q], xv = xp[q];
      acc += xv.x * wv.x + xv.y * wv.y + xv.z * wv.z + xv.w * wv.w;
    }
    ob[p] = acc;
  }
}

// ---------------------------------------------------------------------------
extern "C" void kernel_launch(void* const* d_in, const int* in_sizes, int n_in,
                              void* d_out, int out_size, void* d_ws, size_t ws_size,
                              hipStream_t stream) {
  const float* x    = (const float*)d_in[0];
  const void*  mask = d_in[1];
  const float* W    = (const float*)d_in[2];
  const float* bias = (const float*)d_in[3];
  const float* v    = (const float*)d_in[4];
  float* out = (float*)d_out;

  char* wsb = (char*)d_ws;
  int*   flag = (int*)wsb;                                   // 256 B
  float* s    = (float*)(wsb + 256);                         // 131072 B
  float* wgt  = (float*)(wsb + 131328);                      // 261632 B (fallback only)
  __hip_bfloat16* Wts = (__hip_bfloat16*)(wsb + 393216);     // 524288 B
  __hip_bfloat16* xTs = (__hip_bfloat16*)(wsb + 917504);     // 32 MiB
  __hip_bfloat16* xbf = (__hip_bfloat16*)(wsb + 917504 + 33554432); // 32 MiB
  const size_t NEED = 917504 + 33554432 + 33554432;

  if (ws_size >= NEED) {
    stage1<<<4096 + 129, 256, 0, stream>>>(x, xTs, xbf,
        (const unsigned char*)mask, flag, W, Wts);
    gemm_bf16<<<256, 512, 0, stream>>>(xTs, Wts, bias, v, s);
    pool2<<<dim3(64, Bsz), 256, 0, stream>>>(xbf, s, mask, flag, out);
  } else {
    detect_mask<<<1, 256, 0, stream>>>((const unsigned char*)mask, flag);
    gemm_s_f32<<<dim3(Lsz / 64, Bsz), 256, 0, stream>>>(x, W, bias, v, s);
    win_weights<<<(Bsz * LPOOL + 255) / 256, 256, 0, stream>>>(s, mask, flag, wgt);
    pool_out<<<Bsz * Csz, 256, 0, stream>>>(x, wgt, out);
  }
}

// Round 7
// 161.199 us; speedup vs baseline: 1.0519x; 1.0519x over previous
//
#include <hip/hip_runtime.h>
#include <hip/hip_bf16.h>
#include <cmath>

#define Bsz 8
#define Csz 512
#define Lsz 4096
#define LPOOL 511
#define NEGV -1000000000.0f

typedef __attribute__((ext_vector_type(8))) short short8;
typedef __attribute__((ext_vector_type(4))) float float4v;

__device__ __forceinline__ float bf2f(short u) {
  unsigned int x = ((unsigned int)(unsigned short)u) << 16;
  return __builtin_bit_cast(float, x);
}

// async global->LDS, 16B per lane. Global address is PER-LANE (include lane!);
// LDS dest = wave-uniform base + lane*16 (HW-defined).
__device__ __forceinline__ void gl_lds16(const __hip_bfloat16* g, void* l) {
  __builtin_amdgcn_global_load_lds(
      (const __attribute__((address_space(1))) unsigned int*)g,
      (__attribute__((address_space(3))) unsigned int*)l, 16, 0, 0);
}

// ---------------------------------------------------------------------------
// stage1: flat grid 4096+129 blocks.
//  bid<4096: transpose tile -> xTs (tiled bf16 for MFMA) AND xbf (natural bf16)
//  bid>=4096: prep jobs: mask-width detect / convert W -> Wts tiled.
__global__ __launch_bounds__(256) void stage1(const float* __restrict__ x,
    __hip_bfloat16* __restrict__ xTs, __hip_bfloat16* __restrict__ xbf,
    const unsigned char* __restrict__ mb, int* __restrict__ flag,
    const float* __restrict__ W, __hip_bfloat16* __restrict__ Wts) {
  const int tid = threadIdx.x;
  const int bid = blockIdx.x;
  if (bid < 4096) {
    __shared__ float sX[64][65];               // 65 pitch: conflict-free
    const int lt = bid & 63, ct = (bid >> 6) & 7, b = bid >> 9;
    const int l0 = lt * 64;
    const float* xb = x + ((size_t)b * Csz + ct * 64) * Lsz + l0;
    #pragma unroll
    for (int it = 0; it < 4; ++it) {
      int c = it * 16 + (tid >> 4);
      int l = (tid & 15) * 4;
      *(float4*)(&sX[c][l]) = *(const float4*)(xb + (size_t)c * Lsz + l);
    }
    __syncthreads();
    // tiled layout for MFMA staging
    #pragma unroll
    for (int it = 0; it < 2; ++it) {
      int u = it * 256 + tid;
      int cg = u >> 6, ll = u & 63;
      __hip_bfloat16 hb[8];
      #pragma unroll
      for (int j = 0; j < 8; ++j)
        hb[j] = __float2bfloat16(sX[cg * 8 + j][ll]);
      int m = b * Lsz + l0 + ll;
      int mt = m >> 7, row = m & 127;
      int cglob = ct * 64 + cg * 8;
      int ks = cglob >> 5, seg = (cglob >> 3) & 3;
      *(short8*)(xTs + (((size_t)mt * 16 + ks) * 512 + seg * 128 + row) * 8) = *(short8*)hb;
    }
    // natural layout bf16 copy for pool
    #pragma unroll
    for (int it = 0; it < 2; ++it) {
      int u = it * 256 + tid;
      int cg = u >> 3, lseg = u & 7;
      __hip_bfloat16 hb[8];
      #pragma unroll
      for (int j = 0; j < 8; ++j)
        hb[j] = __float2bfloat16(sX[cg][lseg * 8 + j]);
      *(short8*)(xbf + ((size_t)b * Csz + ct * 64 + cg) * Lsz + l0 + lseg * 8) = *(short8*)hb;
    }
  } else {
    const int pb = bid - 4096;
    if (pb == 0) {
      __shared__ int sf;
      if (tid == 0) sf = 0;
      __syncthreads();
      int f = 0;
      for (int i = tid; i < 4096; i += 256)
        if ((i & 3) && mb[i]) f = 1;
      if (f) atomicOr(&sf, 1);
      __syncthreads();
      if (tid == 0) *flag = sf;  // 0 = int32 mask, 1 = uint8 mask
    } else {
      int tg = (pb - 1) * 256 + tid;
      int d = tg >> 6, cg = tg & 63;
      float4 w0 = *(const float4*)(W + (size_t)d * 512 + cg * 8);
      float4 w1 = *(const float4*)(W + (size_t)d * 512 + cg * 8 + 4);
      __hip_bfloat16 hb[8];
      hb[0] = __float2bfloat16(w0.x); hb[1] = __float2bfloat16(w0.y);
      hb[2] = __float2bfloat16(w0.z); hb[3] = __float2bfloat16(w0.w);
      hb[4] = __float2bfloat16(w1.x); hb[5] = __float2bfloat16(w1.y);
      hb[6] = __float2bfloat16(w1.z); hb[7] = __float2bfloat16(w1.w);
      int nt = d >> 7, row = d & 127, ks = cg >> 2, seg = cg & 3;
      *(short8*)(Wts + (((size_t)nt * 16 + ks) * 512 + seg * 128 + row) * 8) = *(short8*)hb;
    }
  }
}

// ---------------------------------------------------------------------------
// GEMM: s_part[ns][m] = sum_{d in ns-half} tanh(z[m,d]+bias[d])*v[d]
// Block = 64m x 256n, 256 thr = 4 waves (wave = nqq, each 64m x 64n).
// A: one gl_lds/wave/ks into double-buffered LDS (ONE barrier per ks).
// B: direct global->VGPR loads (Wts is 0.5 MB, L2-resident) - never barriered.
// Grid (512 mt, 2 ns) = 1024 blocks -> 4 blocks/CU for barrier overlap.
__global__ __launch_bounds__(256, 4) void gemm_bf16(
    const __hip_bfloat16* __restrict__ xTs, const __hip_bfloat16* __restrict__ Wts,
    const float* __restrict__ bias, const float* __restrict__ v,
    float* __restrict__ s) {
  __shared__ short8 sA[2][256];                // [buf][seg(4)*64+row(64)] 8 KB
  __shared__ float s_acc[64];
  const int tid = threadIdx.x;
  const int lane = tid & 63, wave = tid >> 6;  // wave = nqq (n-quarter of 256)
  const int lr = lane & 15, quad = lane >> 4;
  const int mtp = blockIdx.x, ns = blockIdx.y;
  const int mt = mtp >> 1, mhalf = mtp & 1;    // xTs tiles are 128-m granular
  const int nt = 2 * ns + (wave >> 1);         // Wts tiles are 128-n granular
  const int nh64 = (wave & 1) * 64;

  if (tid < 64) s_acc[tid] = 0.f;

  float bl[4], vl[4];
  #pragma unroll
  for (int nf = 0; nf < 4; ++nf) {
    int n = ns * 256 + wave * 64 + nf * 16 + lr;
    bl[nf] = bias[n]; vl[nf] = v[n];
  }

  // per-lane global bases (in short8 units)
  const __hip_bfloat16* aBase = xTs +
      (((size_t)mt * 16) * 512 + wave * 128 + mhalf * 64 + lane) * 8;
  const short8* bBase = (const short8*)Wts +
      ((size_t)nt * 16) * 512 + quad * 128 + nh64 + lr;

  float4v acc[4][4];
  #pragma unroll
  for (int i = 0; i < 4; ++i)
    #pragma unroll
    for (int j = 0; j < 4; ++j) acc[i][j] = (float4v)0.f;

  // prologue: stage A(ks=0) into buf 0
  gl_lds16(aBase, &sA[0][wave * 64]);

  int buf = 0;
  for (int ks = 0; ks < 16; ++ks) {
    __syncthreads();                           // A(ks) resident; buf^1 free
    if (ks < 15)
      gl_lds16(aBase + (size_t)(ks + 1) * 512 * 8, &sA[buf ^ 1][wave * 64]);
    short8 bfr[4];
    #pragma unroll
    for (int nf = 0; nf < 4; ++nf)
      bfr[nf] = bBase[(size_t)ks * 512 + nf * 16];
    short8 af[4];
    #pragma unroll
    for (int mf = 0; mf < 4; ++mf)
      af[mf] = sA[buf][quad * 64 + mf * 16 + lr];
    #pragma unroll
    for (int mf = 0; mf < 4; ++mf)
      #pragma unroll
      for (int nf = 0; nf < 4; ++nf)
        acc[mf][nf] = __builtin_amdgcn_mfma_f32_16x16x32_bf16(af[mf], bfr[nf], acc[mf][nf], 0, 0, 0);
    buf ^= 1;
  }

  // Epilogue: C/D: n = lane&15, m = quad*4+reg. Reduce over n.
  __syncthreads();
  #pragma unroll
  for (int mf = 0; mf < 4; ++mf) {
    #pragma unroll
    for (int reg = 0; reg < 4; ++reg) {
      float p = 0.f;
      #pragma unroll
      for (int nf = 0; nf < 4; ++nf)
        p += tanhf(acc[mf][nf][reg] + bl[nf]) * vl[nf];
      p += __shfl_xor(p, 1, 16);
      p += __shfl_xor(p, 2, 16);
      p += __shfl_xor(p, 4, 16);
      p += __shfl_xor(p, 8, 16);
      if (lr == 0)
        atomicAdd(&s_acc[mf * 16 + quad * 4 + reg], p);
    }
  }
  __syncthreads();
  if (tid < 64) s[(size_t)ns * 32768 + mtp * 64 + tid] = s_acc[tid];
}

// ---------------------------------------------------------------------------
// pool2: fused windowed-softmax + pooling. s arrives as two ns-partials.
__global__ __launch_bounds__(256) void pool2(const __hip_bfloat16* __restrict__ xbf,
    const float* __restrict__ s, const void* __restrict__ mask,
    const int* __restrict__ flag, float* __restrict__ out) {
  __shared__ float wl[8][17];                  // 17 pitch: conflict-free
  const int t = threadIdx.x;
  const int p0 = blockIdx.x * 8, b = blockIdx.y;
  if (t < 8 && p0 + t < LPOOL) {
    const int p = p0 + t;
    const bool u8 = (*flag != 0);
    const unsigned char* m8 = (const unsigned char*)mask;
    const int* m32 = (const int*)mask;
    const int base = b * Lsz + p * 8;
    float sv[16]; int mv[16];
    float mx = -3.4e38f;
    #pragma unroll
    for (int w = 0; w < 16; ++w) {
      int mk = u8 ? (int)m8[base + w] : m32[base + w];
      float val = mk ? NEGV : (s[base + w] + s[32768 + base + w]);
      sv[w] = val; mv[w] = mk;
      mx = fmaxf(mx, val);
    }
    float sum = 0.f;
    #pragma unroll
    for (int w = 0; w < 16; ++w) { sv[w] = expf(sv[w] - mx); sum += sv[w]; }
    float inv = 1.0f / sum;
    float norm = 0.f;
    #pragma unroll
    for (int w = 0; w < 16; ++w) { sv[w] = mv[w] ? 0.f : sv[w] * inv; norm += sv[w]; }
    norm = fmaxf(norm, 1e-6f);
    float rn = 1.0f / norm;
    #pragma unroll
    for (int w = 0; w < 16; ++w) wl[t][w] = sv[w] * rn;
  }
  __syncthreads();
  const int ci = t >> 3, pi = t & 7;
  const int p = p0 + pi;
  if (p >= LPOOL) return;
  float wr[16];
  #pragma unroll
  for (int w = 0; w < 16; ++w) wr[w] = wl[pi][w];
  #pragma unroll 4
  for (int it = 0; it < 16; ++it) {
    int c = it * 32 + ci;
    const __hip_bfloat16* xp = xbf + ((size_t)b * Csz + c) * Lsz + 8 * p;
    short8 lo = *(const short8*)xp;
    short8 hi = *(const short8*)(xp + 8);
    float acc = 0.f;
    #pragma unroll
    for (int j = 0; j < 8; ++j)
      acc += bf2f(lo[j]) * wr[j] + bf2f(hi[j]) * wr[8 + j];
    out[((size_t)b * Csz + c) * LPOOL + p] = acc;
  }
}

// ---------------------------------------------------------------------------
// Fallback path kernels (only if ws too small for bf16 path)
__global__ void detect_mask(const unsigned char* __restrict__ mb, int* __restrict__ flag) {
  __shared__ int sf;
  int t = threadIdx.x;
  if (t == 0) sf = 0;
  __syncthreads();
  int f = 0;
  for (int i = t; i < 4096; i += 256)
    if ((i & 3) && mb[i]) f = 1;
  if (f) atomicOr(&sf, 1);
  __syncthreads();
  if (t == 0) *flag = sf;
}

__global__ __launch_bounds__(256) void gemm_s_f32(const float* __restrict__ x,
    const float* __restrict__ W, const float* __restrict__ bias,
    const float* __restrict__ v, float* __restrict__ s_out) {
  __shared__ float sA[32][64];
  __shared__ float sB[32][68];
  __shared__ float s_acc[64];
  const int tid = threadIdx.x;
  const int b = blockIdx.y;
  const int l0 = blockIdx.x * 64;
  if (tid < 64) s_acc[tid] = 0.0f;
  const int tx = tid & 15;
  const int ty = tid >> 4;
  const float* xb = x + ((size_t)b * Csz) * Lsz + l0;
  for (int d0 = 0; d0 < Csz; d0 += 64) {
    float acc[4][4] = {{0.f}};
    for (int c0 = 0; c0 < Csz; c0 += 32) {
      __syncthreads();
      #pragma unroll
      for (int it = 0; it < 8; ++it) {
        int idx = tid + it * 256;
        int kc = idx >> 6, ml = idx & 63;
        sA[kc][ml] = xb[(size_t)(c0 + kc) * Lsz + ml];
      }
      #pragma unroll
      for (int it = 0; it < 8; ++it) {
        int idx = tid + it * 256;
        int kc = idx & 31, dj = idx >> 5;
        sB[kc][dj] = W[(size_t)(d0 + dj) * Csz + c0 + kc];
      }
      __syncthreads();
      #pragma unroll
      for (int kc = 0; kc < 32; ++kc) {
        float4 a  = *(const float4*)(&sA[kc][tx << 2]);
        float4 w4 = *(const float4*)(&sB[kc][ty << 2]);
        acc[0][0] += a.x * w4.x; acc[0][1] += a.x * w4.y; acc[0][2] += a.x * w4.z; acc[0][3] += a.x * w4.w;
        acc[1][0] += a.y * w4.x; acc[1][1] += a.y * w4.y; acc[1][2] += a.y * w4.z; acc[1][3] += a.y * w4.w;
        acc[2][0] += a.z * w4.x; acc[2][1] += a.z * w4.y; acc[2][2] += a.z * w4.z; acc[2][3] += a.z * w4.w;
        acc[3][0] += a.w * w4.x; acc[3][1] += a.w * w4.y; acc[3][2] += a.w * w4.z; acc[3][3] += a.w * w4.w;
      }
    }
    float part[4] = {0.f, 0.f, 0.f, 0.f};
    #pragma unroll
    for (int j = 0; j < 4; ++j) {
      int d = d0 + (ty << 2) + j;
      float bj = bias[d], vj = v[d];
      #pragma unroll
      for (int i = 0; i < 4; ++i)
        part[i] += tanhf(acc[i][j] + bj) * vj;
    }
    #pragma unroll
    for (int i = 0; i < 4; ++i)
      atomicAdd(&s_acc[(tx << 2) + i], part[i]);
  }
  __syncthreads();
  if (tid < 64) s_out[(size_t)b * Lsz + l0 + tid] = s_acc[tid];
}

__global__ void win_weights(const float* __restrict__ s, const void* __restrict__ mask,
                            const int* __restrict__ flag, float* __restrict__ wgt) {
  int t = blockIdx.x * blockDim.x + threadIdx.x;
  if (t >= Bsz * LPOOL) return;
  int b = t / LPOOL, p = t - b * LPOOL;
  const bool u8 = (*flag != 0);
  const unsigned char* m8 = (const unsigned char*)mask;
  const int* m32 = (const int*)mask;
  float sv[16]; int mv[16];
  float mx = -3.4e38f;
  int base = b * Lsz + p * 8;
  #pragma unroll
  for (int w = 0; w < 16; ++w) {
    int mk = u8 ? (int)m8[base + w] : m32[base + w];
    float val = mk ? NEGV : s[base + w];
    sv[w] = val; mv[w] = mk;
    mx = fmaxf(mx, val);
  }
  float sum = 0.f;
  #pragma unroll
  for (int w = 0; w < 16; ++w) { sv[w] = expf(sv[w] - mx); sum += sv[w]; }
  float inv = 1.0f / sum;
  float norm = 0.f;
  #pragma unroll
  for (int w = 0; w < 16; ++w) { sv[w] = mv[w] ? 0.f : sv[w] * inv; norm += sv[w]; }
  norm = fmaxf(norm, 1e-6f);
  float rn = 1.0f / norm;
  #pragma unroll
  for (int w = 0; w < 16; ++w) wgt[t * 16 + w] = sv[w] * rn;
}

__global__ __launch_bounds__(256) void pool_out(const float* __restrict__ x,
    const float* __restrict__ wgt, float* __restrict__ out) {
  __shared__ float xrow[Lsz];
  int bc = blockIdx.x;
  int c = bc & (Csz - 1);
  int b = bc >> 9;
  const float* xr = x + ((size_t)b * Csz + c) * Lsz;
  int tid = threadIdx.x;
  #pragma unroll
  for (int it = 0; it < 4; ++it) {
    int idx = (tid + it * 256) << 2;
    *(float4*)(&xrow[idx]) = *(const float4*)(&xr[idx]);
  }
  __syncthreads();
  const float* wb = wgt + (size_t)b * LPOOL * 16;
  float* ob = out + ((size_t)b * Csz + c) * LPOOL;
  for (int p = tid; p < LPOOL; p += 256) {
    const float4* wp = (const float4*)(wb + p * 16);
    const float4* xp = (const float4*)(&xrow[p * 8]);
    float acc = 0.f;
    #pragma unroll
    for (int q = 0; q < 4; ++q) {
      float4 wv = wp[q], xv = xp[q];
      acc += xv.x * wv.x + xv.y * wv.y + xv.z * wv.z + xv.w * wv.w;
    }
    ob[p] = acc;
  }
}

// ---------------------------------------------------------------------------
extern "C" void kernel_launch(void* const* d_in, const int* in_sizes, int n_in,
                              void* d_out, int out_size, void* d_ws, size_t ws_size,
                              hipStream_t stream) {
  const float* x    = (const float*)d_in[0];
  const void*  mask = d_in[1];
  const float* W    = (const float*)d_in[2];
  const float* bias = (const float*)d_in[3];
  const float* v    = (const float*)d_in[4];
  float* out = (float*)d_out;

  char* wsb = (char*)d_ws;
  int*   flag = (int*)wsb;                                   // 512 B
  float* s    = (float*)(wsb + 512);                         // 2 x 32768 fp32 = 262144 B
  float* wgt  = (float*)(wsb + 262656);                      // 261632 B (fallback only)
  __hip_bfloat16* Wts = (__hip_bfloat16*)(wsb + 524288);     // 524288 B
  __hip_bfloat16* xTs = (__hip_bfloat16*)(wsb + 1048576);    // 32 MiB
  __hip_bfloat16* xbf = (__hip_bfloat16*)(wsb + 1048576 + 33554432); // 32 MiB
  const size_t NEED = 1048576 + 33554432 + 33554432;

  if (ws_size >= NEED) {
    stage1<<<4096 + 129, 256, 0, stream>>>(x, xTs, xbf,
        (const unsigned char*)mask, flag, W, Wts);
    gemm_bf16<<<dim3(512, 2), 256, 0, stream>>>(xTs, Wts, bias, v, s);
    pool2<<<dim3(64, Bsz), 256, 0, stream>>>(xbf, s, mask, flag, out);
  } else {
    detect_mask<<<1, 256, 0, stream>>>((const unsigned char*)mask, flag);
    gemm_s_f32<<<dim3(Lsz / 64, Bsz), 256, 0, stream>>>(x, W, bias, v, s);
    win_weights<<<(Bsz * LPOOL + 255) / 256, 256, 0, stream>>>(s, mask, flag, wgt);
    pool_out<<<Bsz * Csz, 256, 0, stream>>>(x, wgt, out);
  }
}